// Round 3
// baseline (590.118 us; speedup 1.0000x reference)
//
#include <hip/hip_runtime.h>

// PPNet forward, round 3.
// - One fused kernel per layer: g1 -> g2(gate, packed bf16 in regs) -> h ->
//   BN*gate epilogue -> store X_next + NEXT layer's BN stats (GEMM + atomics).
// - SC/SH (BN affine) computed per-block in the prologue from gsum/gssq
//   (mlp bias cancels in BN; fin_k eliminated).
// - Single 32KB LDS buffer reused by every phase -> 4 blocks/CU.
// Dispatches: prep, embed, stats0, fused0, fused1, fused2(final dot+select).

typedef __attribute__((ext_vector_type(8))) short short8;
typedef __attribute__((ext_vector_type(4))) float floatx4;

#define BATCH 32768
#define NDOM 4
#define TM 64

__device__ __forceinline__ unsigned short f2b(float f) {
    unsigned u = __float_as_uint(f);
    u += 0x7fffu + ((u >> 16) & 1u);  // round-to-nearest-even
    return (unsigned short)(u >> 16);
}
__device__ __forceinline__ float b2f(unsigned short h) {
    return __uint_as_float(((unsigned)h) << 16);
}

// ---------------------------------------------------------------------------
// Weight prep: fp32 (D,K,N) -> bf16 (D,N,K) packed; zero stat accumulators.
struct MatDesc { const float* src; unsigned K, N, pfx, total; };
struct PrepArgs { MatDesc m[9]; float* stats; unsigned statsN; unsigned grand; };

__global__ __launch_bounds__(256) void prep_k(PrepArgs a, unsigned short* __restrict__ wt) {
    unsigned e = blockIdx.x * 256 + threadIdx.x;
    if (e < a.statsN) a.stats[e] = 0.f;
    if (e >= a.grand) return;
    int j = 0;
    while (j < 8 && e >= a.m[j].pfx + a.m[j].total) j++;
    const unsigned K = a.m[j].K, N = a.m[j].N;
    const unsigned local = e - a.m[j].pfx;
    const unsigned kn = K * N;
    const unsigned d = local / kn;
    const unsigned r2 = local - d * kn;
    const unsigned n = r2 / K;
    const unsigned k = r2 - n * K;
    wt[e] = f2b(a.m[j].src[((long long)d * K + k) * N + n]);
}

// ---------------------------------------------------------------------------
__global__ __launch_bounds__(256) void embed_k(const int* __restrict__ idi, const int* __restrict__ agi,
                                               const float* __restrict__ idt, const float* __restrict__ agt,
                                               unsigned short* __restrict__ gin) {
    int t = blockIdx.x * 256 + threadIdx.x;  // B*16 threads, one per (b, 16-elem slot)
    int b = t >> 4, slot = t & 15;
    int f = slot & 7;
    const int* ip = (slot < 8) ? idi : agi;
    const float* tab = (slot < 8) ? idt : agt;
    int ix = ip[b * 8 + f];
    const float* src = tab + ((long long)f * 100000 + ix) * 16;
    unsigned short tmp[16];
#pragma unroll
    for (int j = 0; j < 16; j++) tmp[j] = f2b(src[j]);
    unsigned short* dst = gin + (long long)b * 256 + slot * 16;
    *(uint4*)dst = *(const uint4*)tmp;
    *(uint4*)(dst + 8) = *(const uint4*)(tmp + 8);
}

// ---------------------------------------------------------------------------
// Stats GEMM for layer 0: acc = gin@Wm0, accumulate per-(d,n) sum & sumsq.
__global__ __launch_bounds__(256, 3) void stats_k(
    const unsigned short* __restrict__ X,
    const unsigned short* __restrict__ Wm,
    float* __restrict__ gsum, float* __restrict__ gssq) {
    constexpr int N = 256, KX = 256, GX = KX / 8, CT = 4;
    __shared__ __align__(16) unsigned short tA[TM * KX];
    const int t = threadIdx.x;
    const int d = blockIdx.y;
    const int m0 = blockIdx.x * TM;
    const unsigned short* Xp = X + (long long)m0 * KX;
#pragma unroll
    for (int r = 0; r < TM * GX / 256; r++) {
        int idx = r * 256 + t;
        int m = idx / GX, j = idx % GX;
        uint4 v = *(const uint4*)(Xp + (long long)m * KX + j * 8);
        *(uint4*)&tA[(m * GX + (j ^ (m & 7))) * 8] = v;
    }
    __syncthreads();
    const int w = t >> 6, lane = t & 63, lrow = lane & 15, lq = lane >> 4;
    const int n0w = w * 64;
    const unsigned short* Wp = Wm + ((long long)d * N + n0w) * KX;
    floatx4 acc[4][CT];
#pragma unroll
    for (int rt = 0; rt < 4; rt++)
#pragma unroll
        for (int ct = 0; ct < CT; ct++) acc[rt][ct] = (floatx4)(0.f);
#pragma unroll
    for (int k0 = 0; k0 < KX; k0 += 32) {
        short8 a[4], b[CT];
#pragma unroll
        for (int rt = 0; rt < 4; rt++) {
            int m = rt * 16 + lrow;
            a[rt] = *(const short8*)&tA[(m * GX + (((k0 >> 3) | lq) ^ (m & 7))) * 8];
        }
#pragma unroll
        for (int ct = 0; ct < CT; ct++)
            b[ct] = *(const short8*)(Wp + (long long)(ct * 16 + lrow) * KX + k0 + lq * 8);
#pragma unroll
        for (int rt = 0; rt < 4; rt++)
#pragma unroll
            for (int ct = 0; ct < CT; ct++)
                acc[rt][ct] = __builtin_amdgcn_mfma_f32_16x16x32_bf16(a[rt], b[ct], acc[rt][ct], 0, 0, 0);
    }
#pragma unroll
    for (int ct = 0; ct < CT; ct++) {
        float s = 0.f, ss = 0.f;
#pragma unroll
        for (int rt = 0; rt < 4; rt++)
#pragma unroll
            for (int r = 0; r < 4; r++) { float v = acc[rt][ct][r]; s += v; ss += v * v; }
        s += __shfl_down(s, 32); ss += __shfl_down(ss, 32);
        s += __shfl_down(s, 16); ss += __shfl_down(ss, 16);
        if (lane < 16) {
            atomicAdd(&gsum[d * N + n0w + ct * 16 + lane], s);
            atomicAdd(&gssq[d * N + n0w + ct * 16 + lane], ss);
        }
    }
}

// ---------------------------------------------------------------------------
// Fused layer kernel. N: this layer's width. KX: h-input width. NN: next
// layer's width (0 = last layer -> final dot+select instead of store).
// GINH: h-input is gin (layer 0, no d offset).
template <int N, int KX, int NN, bool GINH, bool FINAL>
__global__ __launch_bounds__(256, 3) void fused_k(
    const unsigned short* __restrict__ gin,
    const unsigned short* __restrict__ Xh,
    const unsigned short* __restrict__ W1,   // [d][N][256]
    const unsigned short* __restrict__ W2,   // [d][N][N]
    const unsigned short* __restrict__ Wm,   // [d][N][KX]
    const unsigned short* __restrict__ WmN,  // [d][NN][N] (next layer mlp)
    const float* __restrict__ gb1, const float* __restrict__ gb2,
    const float* __restrict__ gsum, const float* __restrict__ gssq,
    const float* __restrict__ gma, const float* __restrict__ bta,
    float* __restrict__ gsumN, float* __restrict__ gssqN,
    unsigned short* __restrict__ Xn,
    const int* __restrict__ dom, const float* __restrict__ fw,
    const float* __restrict__ fb, float* __restrict__ outp, float invB) {
    constexpr int GGn = N / 8;    // granules per row of this layer's outputs
    constexpr int GX = KX / 8;    // granules per row of h-input
    constexpr int CT = N / 64;    // col tiles per wave (NW = N/4)
    constexpr int CTn = (NN > 0) ? (NN / 64) : 1;
    __shared__ __align__(16) unsigned short buf[TM * 256];
    __shared__ float sSC[N], sSH[N];
    __shared__ float sSum[NN > 0 ? NN : 1], sSsq[NN > 0 ? NN : 1];

    const int t = threadIdx.x;
    const int d = blockIdx.y;
    const int m0 = blockIdx.x * TM;
    const int w = t >> 6, lane = t & 63, lrow = lane & 15, lq = lane >> 4;
    const int n0w = w * (N / 4);

    // prologue: BN affine from accumulated stats (bias cancels in BN)
    if (t < N) {
        float ma = gsum[d * N + t] * invB;
        float var = gssq[d * N + t] * invB - ma * ma;
        float sc = rsqrtf(var + 1e-5f) * gma[d * N + t];
        sSC[t] = sc;
        sSH[t] = bta[d * N + t] - ma * sc;
    }
    if (NN > 0 && t < NN) { sSum[t] = 0.f; sSsq[t] = 0.f; }

    {  // stage gin tile (64 x 256), XOR-swizzled 16B granules
        const unsigned short* Gp = gin + (long long)m0 * 256;
#pragma unroll
        for (int r = 0; r < 8; r++) {
            int idx = r * 256 + t;
            int m = idx >> 5, j = idx & 31;
            uint4 v = *(const uint4*)(Gp + (long long)m * 256 + j * 8);
            *(uint4*)&buf[((m << 5) + (j ^ (m & 7))) * 8] = v;
        }
    }
    __syncthreads();

    // ---- g1 = relu(gin @ W1 + b1)
    floatx4 acc1[4][CT];
#pragma unroll
    for (int rt = 0; rt < 4; rt++)
#pragma unroll
        for (int ct = 0; ct < CT; ct++) acc1[rt][ct] = (floatx4)(0.f);
    {
        const unsigned short* W1p = W1 + ((long long)d * N + n0w) * 256;
#pragma unroll
        for (int k0 = 0; k0 < 256; k0 += 32) {
            short8 a[4], b[CT];
#pragma unroll
            for (int rt = 0; rt < 4; rt++) {
                int m = rt * 16 + lrow;
                a[rt] = *(const short8*)&buf[((m << 5) + (((k0 >> 3) | lq) ^ (m & 7))) * 8];
            }
#pragma unroll
            for (int ct = 0; ct < CT; ct++)
                b[ct] = *(const short8*)(W1p + (long long)(ct * 16 + lrow) * 256 + k0 + lq * 8);
#pragma unroll
            for (int rt = 0; rt < 4; rt++)
#pragma unroll
                for (int ct = 0; ct < CT; ct++)
                    acc1[rt][ct] = __builtin_amdgcn_mfma_f32_16x16x32_bf16(a[rt], b[ct], acc1[rt][ct], 0, 0, 0);
        }
    }
    __syncthreads();  // all g1 A-reads done; buf reusable
#pragma unroll
    for (int ct = 0; ct < CT; ct++) {
        int n = n0w + ct * 16 + lrow;
        float bs = gb1[d * N + n];
        int jj = n >> 3, sub = n & 7;
#pragma unroll
        for (int rt = 0; rt < 4; rt++)
#pragma unroll
            for (int r = 0; r < 4; r++) {
                int m = rt * 16 + lq * 4 + r;
                buf[(m * GGn + (jj ^ (m & 7))) * 8 + sub] = f2b(fmaxf(acc1[rt][ct][r] + bs, 0.f));
            }
    }
    __syncthreads();

    // ---- gate = 2*sigmoid(g1 @ W2 + b2), packed bf16 pairs in regs
    floatx4 acc2[4][CT];
#pragma unroll
    for (int rt = 0; rt < 4; rt++)
#pragma unroll
        for (int ct = 0; ct < CT; ct++) acc2[rt][ct] = (floatx4)(0.f);
    {
        const unsigned short* W2p = W2 + ((long long)d * N + n0w) * N;
#pragma unroll
        for (int k0 = 0; k0 < N; k0 += 32) {
            short8 a[4], b[CT];
#pragma unroll
            for (int rt = 0; rt < 4; rt++) {
                int m = rt * 16 + lrow;
                a[rt] = *(const short8*)&buf[(m * GGn + ((((k0 >> 3) | lq)) ^ (m & 7))) * 8];
            }
#pragma unroll
            for (int ct = 0; ct < CT; ct++)
                b[ct] = *(const short8*)(W2p + (long long)(ct * 16 + lrow) * N + k0 + lq * 8);
#pragma unroll
            for (int rt = 0; rt < 4; rt++)
#pragma unroll
                for (int ct = 0; ct < CT; ct++)
                    acc2[rt][ct] = __builtin_amdgcn_mfma_f32_16x16x32_bf16(a[rt], b[ct], acc2[rt][ct], 0, 0, 0);
        }
    }
    unsigned gatep[4][CT][2];
#pragma unroll
    for (int ct = 0; ct < CT; ct++) {
        int n = n0w + ct * 16 + lrow;
        float bs = gb2[d * N + n];
#pragma unroll
        for (int rt = 0; rt < 4; rt++) {
            float g0 = 2.f / (1.f + __expf(-(acc2[rt][ct][0] + bs)));
            float g1 = 2.f / (1.f + __expf(-(acc2[rt][ct][1] + bs)));
            float g2 = 2.f / (1.f + __expf(-(acc2[rt][ct][2] + bs)));
            float g3 = 2.f / (1.f + __expf(-(acc2[rt][ct][3] + bs)));
            gatep[rt][ct][0] = (unsigned)f2b(g0) | ((unsigned)f2b(g1) << 16);
            gatep[rt][ct][1] = (unsigned)f2b(g2) | ((unsigned)f2b(g3) << 16);
        }
    }
    __syncthreads();  // all g2 A-reads done

    {  // restage h-input tile
        const unsigned short* Xp = Xh + ((long long)(GINH ? 0 : d * BATCH) + m0) * KX;
#pragma unroll
        for (int r = 0; r < TM * GX / 256; r++) {
            int idx = r * 256 + t;
            int m = idx / GX, j = idx % GX;
            uint4 v = *(const uint4*)(Xp + (long long)m * KX + j * 8);
            *(uint4*)&buf[(m * GX + (j ^ (m & 7))) * 8] = v;
        }
    }
    __syncthreads();

    // ---- h = X @ Wm (bias folded into SH)
    floatx4 acch[4][CT];
#pragma unroll
    for (int rt = 0; rt < 4; rt++)
#pragma unroll
        for (int ct = 0; ct < CT; ct++) acch[rt][ct] = (floatx4)(0.f);
    {
        const unsigned short* Wmp = Wm + ((long long)d * N + n0w) * KX;
#pragma unroll
        for (int k0 = 0; k0 < KX; k0 += 32) {
            short8 a[4], b[CT];
#pragma unroll
            for (int rt = 0; rt < 4; rt++) {
                int m = rt * 16 + lrow;
                a[rt] = *(const short8*)&buf[(m * GX + (((k0 >> 3) | lq) ^ (m & 7))) * 8];
            }
#pragma unroll
            for (int ct = 0; ct < CT; ct++)
                b[ct] = *(const short8*)(Wmp + (long long)(ct * 16 + lrow) * KX + k0 + lq * 8);
#pragma unroll
            for (int rt = 0; rt < 4; rt++)
#pragma unroll
                for (int ct = 0; ct < CT; ct++)
                    acch[rt][ct] = __builtin_amdgcn_mfma_f32_16x16x32_bf16(a[rt], b[ct], acch[rt][ct], 0, 0, 0);
        }
    }
    __syncthreads();  // all h A-reads done

    // ---- epilogue: X_next = relu(h*SC+SH) * gate -> buf (swizzled)
#pragma unroll
    for (int ct = 0; ct < CT; ct++) {
        int n = n0w + ct * 16 + lrow;
        float sc = sSC[n], sh = sSH[n];
        int jj = n >> 3, sub = n & 7;
#pragma unroll
        for (int rt = 0; rt < 4; rt++) {
            float gv[4] = {b2f((unsigned short)(gatep[rt][ct][0] & 0xffff)),
                           b2f((unsigned short)(gatep[rt][ct][0] >> 16)),
                           b2f((unsigned short)(gatep[rt][ct][1] & 0xffff)),
                           b2f((unsigned short)(gatep[rt][ct][1] >> 16))};
#pragma unroll
            for (int r = 0; r < 4; r++) {
                int m = rt * 16 + lq * 4 + r;
                float v = fmaxf(acch[rt][ct][r] * sc + sh, 0.f) * gv[r];
                buf[(m * GGn + (jj ^ (m & 7))) * 8 + sub] = f2b(v);
            }
        }
    }
    __syncthreads();

    if (!FINAL) {
        // coalesced store of X_next
        unsigned short* Op = Xn + ((long long)d * BATCH + m0) * N;
#pragma unroll
        for (int r = 0; r < TM * GGn / 256; r++) {
            int idx = r * 256 + t;
            int m = idx / GGn, j = idx % GGn;
            *(uint4*)(Op + (long long)m * N + j * 8) = *(const uint4*)&buf[(m * GGn + (j ^ (m & 7))) * 8];
        }
    } else {
        // final: out[b] = sigmoid(x3 . finW[d] + finb[d]) where d == dom[b]
        int m = t >> 2, q = t & 3;
        const float* fwp = fw + d * 64;
        float s = 0.f;
#pragma unroll
        for (int k = 0; k < 16; k++) {
            int c = q * 16 + k;
            s += b2f(buf[(m * 8 + ((c >> 3) ^ (m & 7))) * 8 + (c & 7)]) * fwp[c];
        }
        s += __shfl_down(s, 1);
        s += __shfl_down(s, 2);
        if (q == 0) {
            int b = m0 + m;
            if (dom[b] == d) outp[b] = 1.f / (1.f + __expf(-(s + fb[d])));
        }
    }

    if (NN > 0) {
        // ---- next-layer BN stats: hN_pre = X_next @ WmN, sum/ssq atomics
        const int n0wN = w * (NN / 4);
        floatx4 accs[4][CTn];
#pragma unroll
        for (int rt = 0; rt < 4; rt++)
#pragma unroll
            for (int ct = 0; ct < CTn; ct++) accs[rt][ct] = (floatx4)(0.f);
        const unsigned short* Wnp = WmN + ((long long)d * NN + n0wN) * N;
#pragma unroll
        for (int k0 = 0; k0 < N; k0 += 32) {
            short8 a[4], b[CTn];
#pragma unroll
            for (int rt = 0; rt < 4; rt++) {
                int m = rt * 16 + lrow;
                a[rt] = *(const short8*)&buf[(m * GGn + (((k0 >> 3) | lq) ^ (m & 7))) * 8];
            }
#pragma unroll
            for (int ct = 0; ct < CTn; ct++)
                b[ct] = *(const short8*)(Wnp + (long long)(ct * 16 + lrow) * N + k0 + lq * 8);
#pragma unroll
            for (int rt = 0; rt < 4; rt++)
#pragma unroll
                for (int ct = 0; ct < CTn; ct++)
                    accs[rt][ct] = __builtin_amdgcn_mfma_f32_16x16x32_bf16(a[rt], b[ct], accs[rt][ct], 0, 0, 0);
        }
#pragma unroll
        for (int ct = 0; ct < CTn; ct++) {
            float s = 0.f, ss = 0.f;
#pragma unroll
            for (int rt = 0; rt < 4; rt++)
#pragma unroll
                for (int r = 0; r < 4; r++) { float v = accs[rt][ct][r]; s += v; ss += v * v; }
            s += __shfl_down(s, 32); ss += __shfl_down(ss, 32);
            s += __shfl_down(s, 16); ss += __shfl_down(ss, 16);
            if (lane < 16) {
                atomicAdd(&sSum[n0wN + ct * 16 + lane], s);
                atomicAdd(&sSsq[n0wN + ct * 16 + lane], ss);
            }
        }
        __syncthreads();
        if (t < NN) {
            atomicAdd(&gsumN[d * NN + t], sSum[t]);
            atomicAdd(&gssqN[d * NN + t], sSsq[t]);
        }
    }
}

// ---------------------------------------------------------------------------
extern "C" void kernel_launch(void* const* d_in, const int* in_sizes, int n_in,
                              void* d_out, int out_size, void* d_ws, size_t ws_size,
                              hipStream_t stream) {
    const int B = BATCH, D = NDOM;

    const int* id_idx = (const int*)d_in[0];
    const int* agn_idx = (const int*)d_in[1];
    const int* dom = (const int*)d_in[2];
    const float* id_t = (const float*)d_in[3];
    const float* agn_t = (const float*)d_in[4];
    const float *mlpW[3], *bng[3], *bnb[3], *gW1[3], *gb1[3], *gW2[3], *gb2[3];
    for (int i = 0; i < 3; i++) {
        int b0 = 5 + i * 8;
        mlpW[i] = (const float*)d_in[b0 + 0];
        bng[i] = (const float*)d_in[b0 + 2];
        bnb[i] = (const float*)d_in[b0 + 3];
        gW1[i] = (const float*)d_in[b0 + 4];
        gb1[i] = (const float*)d_in[b0 + 5];
        gW2[i] = (const float*)d_in[b0 + 6];
        gb2[i] = (const float*)d_in[b0 + 7];
    }
    const float* finW = (const float*)d_in[29];
    const float* finb = (const float*)d_in[30];

    char* wsc = (char*)d_ws;
    size_t off = 0;
    auto alloc = [&](size_t bytes) -> char* {
        char* p = wsc + off;
        off = (off + bytes + 255) & ~(size_t)255;
        return p;
    };

    struct { const float* src; int K, N; } mats[9] = {
        {mlpW[0], 256, 256}, {gW1[0], 256, 256}, {gW2[0], 256, 256},
        {mlpW[1], 256, 128}, {gW1[1], 256, 128}, {gW2[1], 128, 128},
        {mlpW[2], 128, 64},  {gW1[2], 256, 64},  {gW2[2], 64, 64}};
    unsigned pfx[10];
    pfx[0] = 0;
    for (int j = 0; j < 9; j++) pfx[j + 1] = pfx[j] + 4u * mats[j].K * mats[j].N;

    unsigned short* wt = (unsigned short*)alloc((size_t)pfx[9] * 2);
    unsigned short* gin = (unsigned short*)alloc((size_t)B * 256 * 2);
    float* stats = (float*)alloc((size_t)3 * 2 * D * 256 * 4);  // per layer: gsum, gssq
    unsigned short* X1 = (unsigned short*)alloc((size_t)D * B * 256 * 2);
    unsigned short* X2 = (unsigned short*)alloc((size_t)D * B * 128 * 2);

    PrepArgs pa;
    for (int j = 0; j < 9; j++) {
        pa.m[j].src = mats[j].src;
        pa.m[j].K = (unsigned)mats[j].K;
        pa.m[j].N = (unsigned)mats[j].N;
        pa.m[j].pfx = pfx[j];
        pa.m[j].total = 4u * mats[j].K * mats[j].N;
    }
    pa.stats = stats;
    pa.statsN = 3 * 2 * D * 256;
    pa.grand = pfx[9];

    const float invB = 1.f / (float)B;
    dim3 gs(B / TM, D);

    prep_k<<<dim3((pfx[9] + 255) / 256), 256, 0, stream>>>(pa, wt);
    embed_k<<<dim3(B * 16 / 256), 256, 0, stream>>>(id_idx, agn_idx, id_t, agn_t, gin);

    float* gsum0 = stats + 0 * 2 * D * 256; float* gssq0 = gsum0 + D * 256;
    float* gsum1 = stats + 1 * 2 * D * 256; float* gssq1 = gsum1 + D * 256;
    float* gsum2 = stats + 2 * 2 * D * 256; float* gssq2 = gsum2 + D * 256;

    // layer-0 stats (h0_pre = gin @ Wm0)
    stats_k<<<gs, 256, 0, stream>>>(gin, wt + pfx[0], gsum0, gssq0);

    // layer 0: N=256, KX=256 (gin), next NN=128
    fused_k<256, 256, 128, true, false><<<gs, 256, 0, stream>>>(
        gin, gin, wt + pfx[1], wt + pfx[2], wt + pfx[0], wt + pfx[3],
        gb1[0], gb2[0], gsum0, gssq0, bng[0], bnb[0], gsum1, gssq1,
        X1, nullptr, nullptr, nullptr, nullptr, invB);

    // layer 1: N=128, KX=256 (X1), next NN=64
    fused_k<128, 256, 64, false, false><<<gs, 256, 0, stream>>>(
        gin, X1, wt + pfx[4], wt + pfx[5], wt + pfx[3], wt + pfx[6],
        gb1[1], gb2[1], gsum1, gssq1, bng[1], bnb[1], gsum2, gssq2,
        X2, nullptr, nullptr, nullptr, nullptr, invB);

    // layer 2: N=64, KX=128 (X2), final dot + sigmoid + domain select
    fused_k<64, 128, 0, false, true><<<gs, 256, 0, stream>>>(
        gin, X2, wt + pfx[7], wt + pfx[8], wt + pfx[6], nullptr,
        gb1[2], gb2[2], gsum2, gssq2, bng[2], bnb[2], nullptr, nullptr,
        nullptr, dom, finW, finb, (float*)d_out, invB);
}

// Round 4
// 527.321 us; speedup vs baseline: 1.1191x; 1.1191x over previous
//
#include <hip/hip_runtime.h>

// PPNet forward, round 4 = round 3 structure with the register-cap bug fixed.
// - One fused kernel per layer: g1 -> g2(gate, packed bf16 in regs) -> h ->
//   BN*gate epilogue -> store X_next + NEXT layer's BN stats (GEMM + atomics).
// - SC/SH (BN affine) computed per-block in the prologue from gsum/gssq.
// - Single 32KB LDS buffer reused by every phase.
// - __launch_bounds__(256,2): round 3's (256,3) made the compiler cap VGPRs
//   at 84 and spill ~256MB of scratch per dispatch (WRITE_SIZE 320MB).
// Dispatches: prep, embed, stats0, fused0, fused1, fused2(final dot+select).

typedef __attribute__((ext_vector_type(8))) short short8;
typedef __attribute__((ext_vector_type(4))) float floatx4;

#define BATCH 32768
#define NDOM 4
#define TM 64

__device__ __forceinline__ unsigned short f2b(float f) {
    unsigned u = __float_as_uint(f);
    u += 0x7fffu + ((u >> 16) & 1u);  // round-to-nearest-even
    return (unsigned short)(u >> 16);
}
__device__ __forceinline__ float b2f(unsigned short h) {
    return __uint_as_float(((unsigned)h) << 16);
}

// ---------------------------------------------------------------------------
// Weight prep: fp32 (D,K,N) -> bf16 (D,N,K) packed; zero stat accumulators.
struct MatDesc { const float* src; unsigned K, N, pfx, total; };
struct PrepArgs { MatDesc m[9]; float* stats; unsigned statsN; unsigned grand; };

__global__ __launch_bounds__(256) void prep_k(PrepArgs a, unsigned short* __restrict__ wt) {
    unsigned e = blockIdx.x * 256 + threadIdx.x;
    if (e < a.statsN) a.stats[e] = 0.f;
    if (e >= a.grand) return;
    int j = 0;
    while (j < 8 && e >= a.m[j].pfx + a.m[j].total) j++;
    const unsigned K = a.m[j].K, N = a.m[j].N;
    const unsigned local = e - a.m[j].pfx;
    const unsigned kn = K * N;
    const unsigned d = local / kn;
    const unsigned r2 = local - d * kn;
    const unsigned n = r2 / K;
    const unsigned k = r2 - n * K;
    wt[e] = f2b(a.m[j].src[((long long)d * K + k) * N + n]);
}

// ---------------------------------------------------------------------------
__global__ __launch_bounds__(256) void embed_k(const int* __restrict__ idi, const int* __restrict__ agi,
                                               const float* __restrict__ idt, const float* __restrict__ agt,
                                               unsigned short* __restrict__ gin) {
    int t = blockIdx.x * 256 + threadIdx.x;  // B*16 threads, one per (b, 16-elem slot)
    int b = t >> 4, slot = t & 15;
    int f = slot & 7;
    const int* ip = (slot < 8) ? idi : agi;
    const float* tab = (slot < 8) ? idt : agt;
    int ix = ip[b * 8 + f];
    const float* src = tab + ((long long)f * 100000 + ix) * 16;
    unsigned short tmp[16];
#pragma unroll
    for (int j = 0; j < 16; j++) tmp[j] = f2b(src[j]);
    unsigned short* dst = gin + (long long)b * 256 + slot * 16;
    *(uint4*)dst = *(const uint4*)tmp;
    *(uint4*)(dst + 8) = *(const uint4*)(tmp + 8);
}

// ---------------------------------------------------------------------------
// Stats GEMM for layer 0: acc = gin@Wm0, accumulate per-(d,n) sum & sumsq.
__global__ __launch_bounds__(256, 2) void stats_k(
    const unsigned short* __restrict__ X,
    const unsigned short* __restrict__ Wm,
    float* __restrict__ gsum, float* __restrict__ gssq) {
    constexpr int N = 256, KX = 256, GX = KX / 8, CT = 4;
    __shared__ __align__(16) unsigned short tA[TM * KX];
    const int t = threadIdx.x;
    const int d = blockIdx.y;
    const int m0 = blockIdx.x * TM;
    const unsigned short* Xp = X + (long long)m0 * KX;
#pragma unroll
    for (int r = 0; r < TM * GX / 256; r++) {
        int idx = r * 256 + t;
        int m = idx / GX, j = idx % GX;
        uint4 v = *(const uint4*)(Xp + (long long)m * KX + j * 8);
        *(uint4*)&tA[(m * GX + (j ^ (m & 7))) * 8] = v;
    }
    __syncthreads();
    const int w = t >> 6, lane = t & 63, lrow = lane & 15, lq = lane >> 4;
    const int n0w = w * 64;
    const unsigned short* Wp = Wm + ((long long)d * N + n0w) * KX;
    floatx4 acc[4][CT];
#pragma unroll
    for (int rt = 0; rt < 4; rt++)
#pragma unroll
        for (int ct = 0; ct < CT; ct++) acc[rt][ct] = (floatx4)(0.f);
#pragma unroll
    for (int k0 = 0; k0 < KX; k0 += 32) {
        short8 a[4], b[CT];
#pragma unroll
        for (int rt = 0; rt < 4; rt++) {
            int m = rt * 16 + lrow;
            a[rt] = *(const short8*)&tA[(m * GX + (((k0 >> 3) | lq) ^ (m & 7))) * 8];
        }
#pragma unroll
        for (int ct = 0; ct < CT; ct++)
            b[ct] = *(const short8*)(Wp + (long long)(ct * 16 + lrow) * KX + k0 + lq * 8);
#pragma unroll
        for (int rt = 0; rt < 4; rt++)
#pragma unroll
            for (int ct = 0; ct < CT; ct++)
                acc[rt][ct] = __builtin_amdgcn_mfma_f32_16x16x32_bf16(a[rt], b[ct], acc[rt][ct], 0, 0, 0);
    }
#pragma unroll
    for (int ct = 0; ct < CT; ct++) {
        float s = 0.f, ss = 0.f;
#pragma unroll
        for (int rt = 0; rt < 4; rt++)
#pragma unroll
            for (int r = 0; r < 4; r++) { float v = acc[rt][ct][r]; s += v; ss += v * v; }
        s += __shfl_down(s, 32); ss += __shfl_down(ss, 32);
        s += __shfl_down(s, 16); ss += __shfl_down(ss, 16);
        if (lane < 16) {
            atomicAdd(&gsum[d * N + n0w + ct * 16 + lane], s);
            atomicAdd(&gssq[d * N + n0w + ct * 16 + lane], ss);
        }
    }
}

// ---------------------------------------------------------------------------
// Fused layer kernel. N: this layer's width. KX: h-input width. NN: next
// layer's width (0 = last layer -> final dot+select instead of store).
// GINH: h-input is gin (layer 0, no d offset).
template <int N, int KX, int NN, bool GINH, bool FINAL>
__global__ __launch_bounds__(256, 2) void fused_k(
    const unsigned short* __restrict__ gin,
    const unsigned short* __restrict__ Xh,
    const unsigned short* __restrict__ W1,   // [d][N][256]
    const unsigned short* __restrict__ W2,   // [d][N][N]
    const unsigned short* __restrict__ Wm,   // [d][N][KX]
    const unsigned short* __restrict__ WmN,  // [d][NN][N] (next layer mlp)
    const float* __restrict__ gb1, const float* __restrict__ gb2,
    const float* __restrict__ gsum, const float* __restrict__ gssq,
    const float* __restrict__ gma, const float* __restrict__ bta,
    float* __restrict__ gsumN, float* __restrict__ gssqN,
    unsigned short* __restrict__ Xn,
    const int* __restrict__ dom, const float* __restrict__ fw,
    const float* __restrict__ fb, float* __restrict__ outp, float invB) {
    constexpr int GGn = N / 8;    // granules per row of this layer's outputs
    constexpr int GX = KX / 8;    // granules per row of h-input
    constexpr int CT = N / 64;    // col tiles per wave (NW = N/4)
    constexpr int CTn = (NN > 0) ? (NN / 64) : 1;
    __shared__ __align__(16) unsigned short buf[TM * 256];
    __shared__ float sSC[N], sSH[N];
    __shared__ float sSum[NN > 0 ? NN : 1], sSsq[NN > 0 ? NN : 1];

    const int t = threadIdx.x;
    const int d = blockIdx.y;
    const int m0 = blockIdx.x * TM;
    const int w = t >> 6, lane = t & 63, lrow = lane & 15, lq = lane >> 4;
    const int n0w = w * (N / 4);

    // prologue: BN affine from accumulated stats (bias cancels in BN)
    if (t < N) {
        float ma = gsum[d * N + t] * invB;
        float var = gssq[d * N + t] * invB - ma * ma;
        float sc = rsqrtf(var + 1e-5f) * gma[d * N + t];
        sSC[t] = sc;
        sSH[t] = bta[d * N + t] - ma * sc;
    }
    if (NN > 0 && t < NN) { sSum[t] = 0.f; sSsq[t] = 0.f; }

    {  // stage gin tile (64 x 256), XOR-swizzled 16B granules
        const unsigned short* Gp = gin + (long long)m0 * 256;
#pragma unroll
        for (int r = 0; r < 8; r++) {
            int idx = r * 256 + t;
            int m = idx >> 5, j = idx & 31;
            uint4 v = *(const uint4*)(Gp + (long long)m * 256 + j * 8);
            *(uint4*)&buf[((m << 5) + (j ^ (m & 7))) * 8] = v;
        }
    }
    __syncthreads();

    // ---- g1 = relu(gin @ W1 + b1)
    floatx4 acc1[4][CT];
#pragma unroll
    for (int rt = 0; rt < 4; rt++)
#pragma unroll
        for (int ct = 0; ct < CT; ct++) acc1[rt][ct] = (floatx4)(0.f);
    {
        const unsigned short* W1p = W1 + ((long long)d * N + n0w) * 256;
#pragma unroll
        for (int k0 = 0; k0 < 256; k0 += 32) {
            short8 a[4], b[CT];
#pragma unroll
            for (int rt = 0; rt < 4; rt++) {
                int m = rt * 16 + lrow;
                a[rt] = *(const short8*)&buf[((m << 5) + (((k0 >> 3) | lq) ^ (m & 7))) * 8];
            }
#pragma unroll
            for (int ct = 0; ct < CT; ct++)
                b[ct] = *(const short8*)(W1p + (long long)(ct * 16 + lrow) * 256 + k0 + lq * 8);
#pragma unroll
            for (int rt = 0; rt < 4; rt++)
#pragma unroll
                for (int ct = 0; ct < CT; ct++)
                    acc1[rt][ct] = __builtin_amdgcn_mfma_f32_16x16x32_bf16(a[rt], b[ct], acc1[rt][ct], 0, 0, 0);
        }
    }
    __syncthreads();  // all g1 A-reads done; buf reusable
#pragma unroll
    for (int ct = 0; ct < CT; ct++) {
        int n = n0w + ct * 16 + lrow;
        float bs = gb1[d * N + n];
        int jj = n >> 3, sub = n & 7;
#pragma unroll
        for (int rt = 0; rt < 4; rt++)
#pragma unroll
            for (int r = 0; r < 4; r++) {
                int m = rt * 16 + lq * 4 + r;
                buf[(m * GGn + (jj ^ (m & 7))) * 8 + sub] = f2b(fmaxf(acc1[rt][ct][r] + bs, 0.f));
            }
    }
    __syncthreads();

    // ---- gate = 2*sigmoid(g1 @ W2 + b2), packed bf16 pairs in regs
    floatx4 acc2[4][CT];
#pragma unroll
    for (int rt = 0; rt < 4; rt++)
#pragma unroll
        for (int ct = 0; ct < CT; ct++) acc2[rt][ct] = (floatx4)(0.f);
    {
        const unsigned short* W2p = W2 + ((long long)d * N + n0w) * N;
#pragma unroll
        for (int k0 = 0; k0 < N; k0 += 32) {
            short8 a[4], b[CT];
#pragma unroll
            for (int rt = 0; rt < 4; rt++) {
                int m = rt * 16 + lrow;
                a[rt] = *(const short8*)&buf[(m * GGn + ((((k0 >> 3) | lq)) ^ (m & 7))) * 8];
            }
#pragma unroll
            for (int ct = 0; ct < CT; ct++)
                b[ct] = *(const short8*)(W2p + (long long)(ct * 16 + lrow) * N + k0 + lq * 8);
#pragma unroll
            for (int rt = 0; rt < 4; rt++)
#pragma unroll
                for (int ct = 0; ct < CT; ct++)
                    acc2[rt][ct] = __builtin_amdgcn_mfma_f32_16x16x32_bf16(a[rt], b[ct], acc2[rt][ct], 0, 0, 0);
        }
    }
    unsigned gatep[4][CT][2];
#pragma unroll
    for (int ct = 0; ct < CT; ct++) {
        int n = n0w + ct * 16 + lrow;
        float bs = gb2[d * N + n];
#pragma unroll
        for (int rt = 0; rt < 4; rt++) {
            float g0 = 2.f / (1.f + __expf(-(acc2[rt][ct][0] + bs)));
            float g1 = 2.f / (1.f + __expf(-(acc2[rt][ct][1] + bs)));
            float g2 = 2.f / (1.f + __expf(-(acc2[rt][ct][2] + bs)));
            float g3 = 2.f / (1.f + __expf(-(acc2[rt][ct][3] + bs)));
            gatep[rt][ct][0] = (unsigned)f2b(g0) | ((unsigned)f2b(g1) << 16);
            gatep[rt][ct][1] = (unsigned)f2b(g2) | ((unsigned)f2b(g3) << 16);
        }
    }
    __syncthreads();  // all g2 A-reads done

    {  // restage h-input tile
        const unsigned short* Xp = Xh + ((long long)(GINH ? 0 : d * BATCH) + m0) * KX;
#pragma unroll
        for (int r = 0; r < TM * GX / 256; r++) {
            int idx = r * 256 + t;
            int m = idx / GX, j = idx % GX;
            uint4 v = *(const uint4*)(Xp + (long long)m * KX + j * 8);
            *(uint4*)&buf[(m * GX + (j ^ (m & 7))) * 8] = v;
        }
    }
    __syncthreads();

    // ---- h = X @ Wm (bias folded into SH)
    floatx4 acch[4][CT];
#pragma unroll
    for (int rt = 0; rt < 4; rt++)
#pragma unroll
        for (int ct = 0; ct < CT; ct++) acch[rt][ct] = (floatx4)(0.f);
    {
        const unsigned short* Wmp = Wm + ((long long)d * N + n0w) * KX;
#pragma unroll
        for (int k0 = 0; k0 < KX; k0 += 32) {
            short8 a[4], b[CT];
#pragma unroll
            for (int rt = 0; rt < 4; rt++) {
                int m = rt * 16 + lrow;
                a[rt] = *(const short8*)&buf[(m * GX + (((k0 >> 3) | lq) ^ (m & 7))) * 8];
            }
#pragma unroll
            for (int ct = 0; ct < CT; ct++)
                b[ct] = *(const short8*)(Wmp + (long long)(ct * 16 + lrow) * KX + k0 + lq * 8);
#pragma unroll
            for (int rt = 0; rt < 4; rt++)
#pragma unroll
                for (int ct = 0; ct < CT; ct++)
                    acch[rt][ct] = __builtin_amdgcn_mfma_f32_16x16x32_bf16(a[rt], b[ct], acch[rt][ct], 0, 0, 0);
        }
    }
    __syncthreads();  // all h A-reads done

    // ---- epilogue: X_next = relu(h*SC+SH) * gate -> buf (swizzled)
#pragma unroll
    for (int ct = 0; ct < CT; ct++) {
        int n = n0w + ct * 16 + lrow;
        float sc = sSC[n], sh = sSH[n];
        int jj = n >> 3, sub = n & 7;
#pragma unroll
        for (int rt = 0; rt < 4; rt++) {
            float gv[4] = {b2f((unsigned short)(gatep[rt][ct][0] & 0xffff)),
                           b2f((unsigned short)(gatep[rt][ct][0] >> 16)),
                           b2f((unsigned short)(gatep[rt][ct][1] & 0xffff)),
                           b2f((unsigned short)(gatep[rt][ct][1] >> 16))};
#pragma unroll
            for (int r = 0; r < 4; r++) {
                int m = rt * 16 + lq * 4 + r;
                float v = fmaxf(acch[rt][ct][r] * sc + sh, 0.f) * gv[r];
                buf[(m * GGn + (jj ^ (m & 7))) * 8 + sub] = f2b(v);
            }
        }
    }
    __syncthreads();

    if (!FINAL) {
        // coalesced store of X_next
        unsigned short* Op = Xn + ((long long)d * BATCH + m0) * N;
#pragma unroll
        for (int r = 0; r < TM * GGn / 256; r++) {
            int idx = r * 256 + t;
            int m = idx / GGn, j = idx % GGn;
            *(uint4*)(Op + (long long)m * N + j * 8) = *(const uint4*)&buf[(m * GGn + (j ^ (m & 7))) * 8];
        }
    } else {
        // final: out[b] = sigmoid(x3 . finW[d] + finb[d]) where d == dom[b]
        int m = t >> 2, q = t & 3;
        const float* fwp = fw + d * 64;
        float s = 0.f;
#pragma unroll
        for (int k = 0; k < 16; k++) {
            int c = q * 16 + k;
            s += b2f(buf[(m * 8 + ((c >> 3) ^ (m & 7))) * 8 + (c & 7)]) * fwp[c];
        }
        s += __shfl_down(s, 1);
        s += __shfl_down(s, 2);
        if (q == 0) {
            int b = m0 + m;
            if (dom[b] == d) outp[b] = 1.f / (1.f + __expf(-(s + fb[d])));
        }
    }

    if (NN > 0) {
        // ---- next-layer BN stats: hN_pre = X_next @ WmN, sum/ssq atomics
        const int n0wN = w * (NN / 4);
        floatx4 accs[4][CTn];
#pragma unroll
        for (int rt = 0; rt < 4; rt++)
#pragma unroll
            for (int ct = 0; ct < CTn; ct++) accs[rt][ct] = (floatx4)(0.f);
        const unsigned short* Wnp = WmN + ((long long)d * NN + n0wN) * N;
#pragma unroll
        for (int k0 = 0; k0 < N; k0 += 32) {
            short8 a[4], b[CTn];
#pragma unroll
            for (int rt = 0; rt < 4; rt++) {
                int m = rt * 16 + lrow;
                a[rt] = *(const short8*)&buf[(m * GGn + (((k0 >> 3) | lq) ^ (m & 7))) * 8];
            }
#pragma unroll
            for (int ct = 0; ct < CTn; ct++)
                b[ct] = *(const short8*)(Wnp + (long long)(ct * 16 + lrow) * N + k0 + lq * 8);
#pragma unroll
            for (int rt = 0; rt < 4; rt++)
#pragma unroll
                for (int ct = 0; ct < CTn; ct++)
                    accs[rt][ct] = __builtin_amdgcn_mfma_f32_16x16x32_bf16(a[rt], b[ct], accs[rt][ct], 0, 0, 0);
        }
#pragma unroll
        for (int ct = 0; ct < CTn; ct++) {
            float s = 0.f, ss = 0.f;
#pragma unroll
            for (int rt = 0; rt < 4; rt++)
#pragma unroll
                for (int r = 0; r < 4; r++) { float v = accs[rt][ct][r]; s += v; ss += v * v; }
            s += __shfl_down(s, 32); ss += __shfl_down(ss, 32);
            s += __shfl_down(s, 16); ss += __shfl_down(ss, 16);
            if (lane < 16) {
                atomicAdd(&sSum[n0wN + ct * 16 + lane], s);
                atomicAdd(&sSsq[n0wN + ct * 16 + lane], ss);
            }
        }
        __syncthreads();
        if (t < NN) {
            atomicAdd(&gsumN[d * NN + t], sSum[t]);
            atomicAdd(&gssqN[d * NN + t], sSsq[t]);
        }
    }
}

// ---------------------------------------------------------------------------
extern "C" void kernel_launch(void* const* d_in, const int* in_sizes, int n_in,
                              void* d_out, int out_size, void* d_ws, size_t ws_size,
                              hipStream_t stream) {
    const int B = BATCH, D = NDOM;

    const int* id_idx = (const int*)d_in[0];
    const int* agn_idx = (const int*)d_in[1];
    const int* dom = (const int*)d_in[2];
    const float* id_t = (const float*)d_in[3];
    const float* agn_t = (const float*)d_in[4];
    const float *mlpW[3], *bng[3], *bnb[3], *gW1[3], *gb1[3], *gW2[3], *gb2[3];
    for (int i = 0; i < 3; i++) {
        int b0 = 5 + i * 8;
        mlpW[i] = (const float*)d_in[b0 + 0];
        bng[i] = (const float*)d_in[b0 + 2];
        bnb[i] = (const float*)d_in[b0 + 3];
        gW1[i] = (const float*)d_in[b0 + 4];
        gb1[i] = (const float*)d_in[b0 + 5];
        gW2[i] = (const float*)d_in[b0 + 6];
        gb2[i] = (const float*)d_in[b0 + 7];
    }
    const float* finW = (const float*)d_in[29];
    const float* finb = (const float*)d_in[30];

    char* wsc = (char*)d_ws;
    size_t off = 0;
    auto alloc = [&](size_t bytes) -> char* {
        char* p = wsc + off;
        off = (off + bytes + 255) & ~(size_t)255;
        return p;
    };

    struct { const float* src; int K, N; } mats[9] = {
        {mlpW[0], 256, 256}, {gW1[0], 256, 256}, {gW2[0], 256, 256},
        {mlpW[1], 256, 128}, {gW1[1], 256, 128}, {gW2[1], 128, 128},
        {mlpW[2], 128, 64},  {gW1[2], 256, 64},  {gW2[2], 64, 64}};
    unsigned pfx[10];
    pfx[0] = 0;
    for (int j = 0; j < 9; j++) pfx[j + 1] = pfx[j] + 4u * mats[j].K * mats[j].N;

    unsigned short* wt = (unsigned short*)alloc((size_t)pfx[9] * 2);
    unsigned short* gin = (unsigned short*)alloc((size_t)B * 256 * 2);
    float* stats = (float*)alloc((size_t)3 * 2 * D * 256 * 4);  // per layer: gsum, gssq
    unsigned short* X1 = (unsigned short*)alloc((size_t)D * B * 256 * 2);
    unsigned short* X2 = (unsigned short*)alloc((size_t)D * B * 128 * 2);

    PrepArgs pa;
    for (int j = 0; j < 9; j++) {
        pa.m[j].src = mats[j].src;
        pa.m[j].K = (unsigned)mats[j].K;
        pa.m[j].N = (unsigned)mats[j].N;
        pa.m[j].pfx = pfx[j];
        pa.m[j].total = 4u * mats[j].K * mats[j].N;
    }
    pa.stats = stats;
    pa.statsN = 3 * 2 * D * 256;
    pa.grand = pfx[9];

    const float invB = 1.f / (float)B;
    dim3 gs(B / TM, D);

    prep_k<<<dim3((pfx[9] + 255) / 256), 256, 0, stream>>>(pa, wt);
    embed_k<<<dim3(B * 16 / 256), 256, 0, stream>>>(id_idx, agn_idx, id_t, agn_t, gin);

    float* gsum0 = stats + 0 * 2 * D * 256; float* gssq0 = gsum0 + D * 256;
    float* gsum1 = stats + 1 * 2 * D * 256; float* gssq1 = gsum1 + D * 256;
    float* gsum2 = stats + 2 * 2 * D * 256; float* gssq2 = gsum2 + D * 256;

    // layer-0 stats (h0_pre = gin @ Wm0)
    stats_k<<<gs, 256, 0, stream>>>(gin, wt + pfx[0], gsum0, gssq0);

    // layer 0: N=256, KX=256 (gin), next NN=128
    fused_k<256, 256, 128, true, false><<<gs, 256, 0, stream>>>(
        gin, gin, wt + pfx[1], wt + pfx[2], wt + pfx[0], wt + pfx[3],
        gb1[0], gb2[0], gsum0, gssq0, bng[0], bnb[0], gsum1, gssq1,
        X1, nullptr, nullptr, nullptr, nullptr, invB);

    // layer 1: N=128, KX=256 (X1), next NN=64
    fused_k<128, 256, 64, false, false><<<gs, 256, 0, stream>>>(
        gin, X1, wt + pfx[4], wt + pfx[5], wt + pfx[3], wt + pfx[6],
        gb1[1], gb2[1], gsum1, gssq1, bng[1], bnb[1], gsum2, gssq2,
        X2, nullptr, nullptr, nullptr, nullptr, invB);

    // layer 2: N=64, KX=128 (X2), final dot + sigmoid + domain select
    fused_k<64, 128, 0, false, true><<<gs, 256, 0, stream>>>(
        gin, X2, wt + pfx[7], wt + pfx[8], wt + pfx[6], nullptr,
        gb1[2], gb2[2], gsum2, gssq2, bng[2], bnb[2], nullptr, nullptr,
        nullptr, dom, finW, finb, (float*)d_out, invB);
}